// Round 1
// baseline (276.065 us; speedup 1.0000x reference)
//
#include <hip/hip_runtime.h>
#include <cstdint>

typedef unsigned short u16;
typedef __attribute__((ext_vector_type(8))) short s16x8;
typedef __attribute__((ext_vector_type(8))) unsigned short u16x8;
typedef __attribute__((ext_vector_type(4))) float f32x4;

__device__ inline u16 f2bf(float f){
  union { float f; uint32_t u; } v; v.f = f;
  uint32_t r = v.u + 0x7fffu + ((v.u >> 16) & 1u);
  return (u16)(r >> 16);
}

__device__ inline f32x4 mfma16(s16x8 a, s16x8 b, f32x4 c){
  return __builtin_amdgcn_mfma_f32_16x16x32_bf16(a, b, c, 0, 0, 0);
}

// ---------------------------------------------------------------- convert q/k/v to bf16
__global__ __launch_bounds__(256) void convert3_kernel(
    const float* __restrict__ q, const float* __restrict__ k, const float* __restrict__ v,
    u16* __restrict__ qo, u16* __restrict__ ko, u16* __restrict__ vo){
  const float* src = (blockIdx.y == 0) ? q : (blockIdx.y == 1) ? k : v;
  u16* dst = (blockIdx.y == 0) ? qo : (blockIdx.y == 1) ? ko : vo;
  size_t i = ((size_t)blockIdx.x * 256 + threadIdx.x) * 8;
  float4 a = *(const float4*)(src + i);
  float4 b = *(const float4*)(src + i + 4);
  u16x8 o = { f2bf(a.x), f2bf(a.y), f2bf(a.z), f2bf(a.w),
              f2bf(b.x), f2bf(b.y), f2bf(b.z), f2bf(b.w) };
  *(u16x8*)(dst + i) = o;
}

// ---------------------------------------------------------------- transpose+convert weights: Wt[n][k] = bf16(W[k][n])
__global__ void transw_kernel(
    const float* __restrict__ W0, const float* __restrict__ W1,
    const float* __restrict__ W2, const float* __restrict__ W3,
    u16* __restrict__ T0, u16* __restrict__ T1, u16* __restrict__ T2, u16* __restrict__ T3){
  const float* W = (blockIdx.z == 0) ? W0 : (blockIdx.z == 1) ? W1 : (blockIdx.z == 2) ? W2 : W3;
  u16* T = (blockIdx.z == 0) ? T0 : (blockIdx.z == 1) ? T1 : (blockIdx.z == 2) ? T2 : T3;
  __shared__ float t[32][33];
  int n0 = blockIdx.x * 32, k0 = blockIdx.y * 32;
  int tx = threadIdx.x, ty = threadIdx.y; // (32,8)
  #pragma unroll
  for (int j = 0; j < 4; j++)
    t[ty + j*8][tx] = W[(size_t)(k0 + ty + j*8) * 1024 + n0 + tx];
  __syncthreads();
  #pragma unroll
  for (int j = 0; j < 4; j++)
    T[(size_t)(n0 + ty + j*8) * 1024 + k0 + tx] = f2bf(t[tx][ty + j*8]);
}

// ---------------------------------------------------------------- pack mask to bits
__global__ __launch_bounds__(256) void packmask_kernel(const int* __restrict__ mask,
                                                       unsigned* __restrict__ bits){
  size_t i = (size_t)blockIdx.x * 256 + threadIdx.x;
  int v = mask[i];
  unsigned long long bal = __ballot(v != 0);
  int lane = threadIdx.x & 63;
  if (lane == 0)       bits[i >> 5] = (unsigned)bal;
  else if (lane == 32) bits[i >> 5] = (unsigned)(bal >> 32);
}

// ---------------------------------------------------------------- ctx = market_context @ Wc + bc  (f32, tiny)
__global__ __launch_bounds__(256) void ctx_kernel(const float* __restrict__ mc,
                                                  const float* __restrict__ Wc,
                                                  const float* __restrict__ bc,
                                                  float* __restrict__ ctx){
  int c = threadIdx.x & 63, kk = threadIdx.x >> 6;
  int col = blockIdx.x * 64 + c;
  float a0 = 0.f, a1 = 0.f;
  for (int k = kk * 256; k < kk * 256 + 256; k++){
    float wv = Wc[(size_t)k * 1024 + col];
    a0 += mc[k] * wv;
    a1 += mc[1024 + k] * wv;
  }
  __shared__ float red[2][4][64];
  red[0][kk][c] = a0; red[1][kk][c] = a1;
  __syncthreads();
  if (threadIdx.x < 64){
    int cc = threadIdx.x;
    ctx[blockIdx.x*64 + cc] = red[0][0][cc] + red[0][1][cc] + red[0][2][cc] + red[0][3][cc]
                              + bc[blockIdx.x*64 + cc];
  } else if (threadIdx.x < 128){
    int cc = threadIdx.x - 64;
    ctx[1024 + blockIdx.x*64 + cc] = red[1][0][cc] + red[1][1][cc] + red[1][2][cc] + red[1][3][cc]
                                     + bc[blockIdx.x*64 + cc];
  }
}

// ---------------------------------------------------------------- GEMM: out = A[4096,1024] @ Wt^T + epilogue
// z=0: ->Qb bf16 natural; z=1: +ctx ->Kb; z=2: ->Vt[B,H,DK,S]; z=3: +resid ->X f32
struct GemmParams {
  const u16* A0; const u16* A1; const u16* A2; const u16* A3;
  const u16* W0; const u16* W1; const u16* W2; const u16* W3;
  const float* b0; const float* b1; const float* b2; const float* b3;
  const float* ctx; const float* resid;
  u16* outQ; u16* outK; u16* outV; float* outX;
  int which;
};

__global__ __launch_bounds__(256) void gemm_kernel(GemmParams P){
  int z = (P.which < 0) ? blockIdx.z : P.which;
  const u16* A; const u16* W;
  if (z == 0){ A = P.A0; W = P.W0; }
  else if (z == 1){ A = P.A1; W = P.W1; }
  else if (z == 2){ A = P.A2; W = P.W2; }
  else { A = P.A3; W = P.W3; }
  const int K = 1024;
  int m0 = blockIdx.y * 128, n0 = blockIdx.x * 128;
  __shared__ u16 Asm[128 * 64];
  __shared__ u16 Bsm[128 * 64];
  int tid = threadIdx.x, lane = tid & 63, w = tid >> 6;
  int li = lane & 15, lq = lane >> 4;
  int wm = w >> 1, wn = w & 1;
  f32x4 zero = {0.f, 0.f, 0.f, 0.f};
  f32x4 acc[4][4];
  #pragma unroll
  for (int i = 0; i < 4; i++)
    #pragma unroll
    for (int j = 0; j < 4; j++) acc[i][j] = zero;

  for (int kt = 0; kt < 16; ++kt){
    int k0 = kt * 64;
    __syncthreads();
    #pragma unroll
    for (int i = 0; i < 4; i++){
      int u = i * 256 + tid, row = u >> 3, slot = u & 7;
      u16x8 va = *(const u16x8*)(A + (size_t)(m0 + row) * K + k0 + slot * 8);
      *(u16x8*)&Asm[row * 64 + ((slot ^ (row & 7)) << 3)] = va;
      u16x8 vb = *(const u16x8*)(W + (size_t)(n0 + row) * K + k0 + slot * 8);
      *(u16x8*)&Bsm[row * 64 + ((slot ^ (row & 7)) << 3)] = vb;
    }
    __syncthreads();
    #pragma unroll
    for (int ks = 0; ks < 2; ++ks){
      s16x8 af[4], bfr[4];
      #pragma unroll
      for (int mb = 0; mb < 4; mb++){
        int row = wm * 64 + mb * 16 + li, slot = ks * 4 + lq;
        af[mb] = *(const s16x8*)&Asm[row * 64 + ((slot ^ (row & 7)) << 3)];
      }
      #pragma unroll
      for (int nb = 0; nb < 4; nb++){
        int row = wn * 64 + nb * 16 + li, slot = ks * 4 + lq;
        bfr[nb] = *(const s16x8*)&Bsm[row * 64 + ((slot ^ (row & 7)) << 3)];
      }
      #pragma unroll
      for (int mb = 0; mb < 4; mb++)
        #pragma unroll
        for (int nb = 0; nb < 4; nb++)
          acc[mb][nb] = mfma16(af[mb], bfr[nb], acc[mb][nb]);
    }
  }
  const float* bias = (z == 0) ? P.b0 : (z == 1) ? P.b1 : (z == 2) ? P.b2 : P.b3;
  #pragma unroll
  for (int mb = 0; mb < 4; mb++){
    #pragma unroll
    for (int nb = 0; nb < 4; nb++){
      int colL = wn * 64 + nb * 16 + li; int col = n0 + colL;
      float bcol = bias[col];
      #pragma unroll
      for (int r = 0; r < 4; r++){
        int row = m0 + wm * 64 + mb * 16 + lq * 4 + r;
        float v = acc[mb][nb][r] + bcol;
        if (z == 0){
          P.outQ[(size_t)row * 1024 + col] = f2bf(v);
        } else if (z == 1){
          v += P.ctx[(size_t)(row >> 11) * 1024 + col];
          P.outK[(size_t)row * 1024 + col] = f2bf(v);
        } else if (z == 2){
          int b = row >> 11, s = row & 2047, h = col >> 6, dk = col & 63;
          P.outV[(((size_t)(b * 16 + h) * 64 + dk) << 11) + s] = f2bf(v);
        } else {
          v += P.resid[(size_t)row * 1024 + col];
          P.outX[(size_t)row * 1024 + col] = v;
        }
      }
    }
  }
}

// ---------------------------------------------------------------- flash attention
// grid (S/64, B*H), block 256 (4 waves; wave w owns q rows w*16..w*16+16)
__global__ __launch_bounds__(256) void attn_kernel(
    const u16* __restrict__ Qg, const u16* __restrict__ Kg, const u16* __restrict__ Vtg,
    const unsigned* __restrict__ mbits, u16* __restrict__ ctx2){
  __shared__ u16 Qs[64 * 64];
  __shared__ u16 Ks[128 * 64];
  __shared__ u16 Vs[64 * 128];
  __shared__ u16 Ps[64 * 128];
  __shared__ unsigned Ms[64 * 4];
  int tid = threadIdx.x, lane = tid & 63, w = tid >> 6;
  int li = lane & 15, lq = lane >> 4;
  int q0 = blockIdx.x * 64, bh = blockIdx.y, b = bh >> 4, h = bh & 15;
  // stage Q tile [64][64]
  #pragma unroll
  for (int i = 0; i < 2; i++){
    int u = i * 256 + tid, row = u >> 3, slot = u & 7;
    u16x8 v = *(const u16x8*)(Qg + (size_t)(b * 2048 + q0 + row) * 1024 + h * 64 + slot * 8);
    *(u16x8*)&Qs[row * 64 + ((slot ^ (row & 7)) << 3)] = v;
  }
  f32x4 zero = {0.f, 0.f, 0.f, 0.f};
  f32x4 O[4];
  float mr[4], lsum[4];
  #pragma unroll
  for (int i = 0; i < 4; i++){ O[i] = zero; mr[i] = -3.0e38f; lsum[i] = 0.f; }

  for (int kt = 0; kt < 16; ++kt){
    int kv0 = kt * 128;
    __syncthreads();
    // stage K tile [128][64]
    #pragma unroll
    for (int i = 0; i < 4; i++){
      int u = i * 256 + tid, row = u >> 3, slot = u & 7;
      u16x8 v = *(const u16x8*)(Kg + (size_t)(b * 2048 + kv0 + row) * 1024 + h * 64 + slot * 8);
      *(u16x8*)&Ks[row * 64 + ((slot ^ (row & 7)) << 3)] = v;
    }
    // stage V^T tile [64][128]
    #pragma unroll
    for (int i = 0; i < 4; i++){
      int u = i * 256 + tid, row = u >> 4, slot = u & 15;
      u16x8 v = *(const u16x8*)(Vtg + (((size_t)(b * 16 + h) * 64 + row) << 11) + kv0 + slot * 8);
      *(u16x8*)&Vs[row * 128 + ((slot ^ (row & 7)) << 3)] = v;
    }
    // stage mask words [64][4]
    {
      int r = tid >> 2, c = tid & 3;
      Ms[tid] = mbits[(size_t)(b * 2048 + q0 + r) * 64 + (kv0 >> 5) + c];
    }
    __syncthreads();

    // S = Q K^T for this wave's 16 q-rows x 128 kv
    f32x4 S[8];
    #pragma unroll
    for (int nb = 0; nb < 8; nb++) S[nb] = zero;
    #pragma unroll
    for (int ks = 0; ks < 2; ++ks){
      int arow = w * 16 + li, aslot = ks * 4 + lq;
      s16x8 a = *(const s16x8*)&Qs[arow * 64 + ((aslot ^ (arow & 7)) << 3)];
      #pragma unroll
      for (int nb = 0; nb < 8; nb++){
        int brow = nb * 16 + li, bslot = ks * 4 + lq;
        s16x8 bb = *(const s16x8*)&Ks[brow * 64 + ((bslot ^ (brow & 7)) << 3)];
        S[nb] = mfma16(a, bb, S[nb]);
      }
    }
    // scale + mask + tile max
    float tmax[4] = {-3.0e38f, -3.0e38f, -3.0e38f, -3.0e38f};
    #pragma unroll
    for (int nb = 0; nb < 8; nb++){
      int bit = (nb * 16 + li) & 31, wi = nb >> 1;
      #pragma unroll
      for (int r = 0; r < 4; r++){
        int qlocal = w * 16 + lq * 4 + r;
        unsigned mw = Ms[qlocal * 4 + wi];
        float s = S[nb][r] * 0.125f;
        s = ((mw >> bit) & 1u) ? s : -3.0e38f;
        S[nb][r] = s;
        tmax[r] = fmaxf(tmax[r], s);
      }
    }
    float alpha[4], tsum[4];
    #pragma unroll
    for (int r = 0; r < 4; r++){
      float v = tmax[r];
      v = fmaxf(v, __shfl_xor(v, 1, 64));
      v = fmaxf(v, __shfl_xor(v, 2, 64));
      v = fmaxf(v, __shfl_xor(v, 4, 64));
      v = fmaxf(v, __shfl_xor(v, 8, 64));
      float mnew = fmaxf(mr[r], v);
      alpha[r] = __expf(mr[r] - mnew);
      mr[r] = mnew;
      tsum[r] = 0.f;
    }
    // p = exp(s - m), write P (bf16, swizzled), row sums
    #pragma unroll
    for (int nb = 0; nb < 8; nb++){
      #pragma unroll
      for (int r = 0; r < 4; r++){
        int qlocal = w * 16 + lq * 4 + r;
        float s = S[nb][r];
        float p = (s <= -1.0e37f) ? 0.f : __expf(s - mr[r]);
        tsum[r] += p;
        int col = nb * 16 + li;
        int slot = col >> 3, e = col & 7;
        Ps[qlocal * 128 + ((slot ^ (qlocal & 7)) << 3) + e] = f2bf(p);
      }
    }
    #pragma unroll
    for (int r = 0; r < 4; r++){
      float v = tsum[r];
      v += __shfl_xor(v, 1, 64);
      v += __shfl_xor(v, 2, 64);
      v += __shfl_xor(v, 4, 64);
      v += __shfl_xor(v, 8, 64);
      lsum[r] = lsum[r] * alpha[r] + v;
      O[0][r] *= alpha[r]; O[1][r] *= alpha[r]; O[2][r] *= alpha[r]; O[3][r] *= alpha[r];
    }
    __syncthreads();
    // O += P @ V
    #pragma unroll
    for (int ks = 0; ks < 4; ++ks){
      int arow = w * 16 + li, aslot = ks * 4 + lq;
      s16x8 pa = *(const s16x8*)&Ps[arow * 128 + ((aslot ^ (arow & 7)) << 3)];
      #pragma unroll
      for (int nd = 0; nd < 4; nd++){
        int brow = nd * 16 + li, bslot = ks * 4 + lq;
        s16x8 vb = *(const s16x8*)&Vs[brow * 128 + ((bslot ^ (brow & 7)) << 3)];
        O[nd] = mfma16(pa, vb, O[nd]);
      }
    }
  }
  // write ctx2 bf16 [B*S, D]
  #pragma unroll
  for (int nd = 0; nd < 4; nd++){
    #pragma unroll
    for (int r = 0; r < 4; r++){
      int row = q0 + w * 16 + lq * 4 + r, col = h * 64 + nd * 16 + li;
      float v = O[nd][r] / lsum[r];
      ctx2[(size_t)(b * 2048 + row) * 1024 + col] = f2bf(v);
    }
  }
}

// ---------------------------------------------------------------- LayerNorm rows of X
__global__ __launch_bounds__(256) void ln_kernel(const float* __restrict__ X,
                                                 const float* __restrict__ g,
                                                 const float* __restrict__ bb,
                                                 float* __restrict__ out){
  size_t row = blockIdx.x;
  const float* x = X + row * 1024;
  int tid = threadIdx.x;
  float4 v = *(const float4*)(x + tid * 4);
  float s = v.x + v.y + v.z + v.w;
  float s2 = v.x*v.x + v.y*v.y + v.z*v.z + v.w*v.w;
  #pragma unroll
  for (int o = 1; o < 64; o <<= 1){
    s += __shfl_xor(s, o, 64);
    s2 += __shfl_xor(s2, o, 64);
  }
  __shared__ float rs[4], rs2[4];
  int w = tid >> 6;
  if ((tid & 63) == 0){ rs[w] = s; rs2[w] = s2; }
  __syncthreads();
  s = rs[0] + rs[1] + rs[2] + rs[3];
  s2 = rs2[0] + rs2[1] + rs2[2] + rs2[3];
  float mu = s * (1.f / 1024.f);
  float var = s2 * (1.f / 1024.f) - mu * mu;
  float rstd = rsqrtf(var + 1e-5f);
  float4 gg = *(const float4*)(g + tid * 4);
  float4 bt = *(const float4*)(bb + tid * 4);
  float4 o;
  o.x = (v.x - mu) * rstd * gg.x + bt.x;
  o.y = (v.y - mu) * rstd * gg.y + bt.y;
  o.z = (v.z - mu) * rstd * gg.z + bt.z;
  o.w = (v.w - mu) * rstd * gg.w + bt.w;
  *(float4*)(out + row * 1024 + tid * 4) = o;
}

// ----------------------------------------------------------------
extern "C" void kernel_launch(void* const* d_in, const int* in_sizes, int n_in,
                              void* d_out, int out_size, void* d_ws, size_t ws_size,
                              hipStream_t stream){
  const float* query = (const float*)d_in[0];
  const float* key_  = (const float*)d_in[1];
  const float* value = (const float*)d_in[2];
  const int*   mask  = (const int*)d_in[3];
  const float* mc    = (const float*)d_in[4];
  const float* Wq = (const float*)d_in[5];  const float* bq = (const float*)d_in[6];
  const float* Wk = (const float*)d_in[7];  const float* bk = (const float*)d_in[8];
  const float* Wv = (const float*)d_in[9];  const float* bv = (const float*)d_in[10];
  const float* Wo = (const float*)d_in[11]; const float* bo = (const float*)d_in[12];
  const float* Wc = (const float*)d_in[13]; const float* bc = (const float*)d_in[14];
  const float* lng = (const float*)d_in[15]; const float* lnb = (const float*)d_in[16];
  float* outp = (float*)d_out;
  uint8_t* ws = (uint8_t*)d_ws;
  const size_t MB = (size_t)1 << 20;
  if (ws_size < 58 * MB) return; // insufficient workspace — fail visibly

  u16* q_bf = (u16*)(ws + 0);        // 8MB, reused as ctx2 after QKV GEMM
  u16* k_bf = (u16*)(ws + 8 * MB);   // 8MB
  u16* v_bf = (u16*)(ws + 16 * MB);  // 8MB
  float* X  = (float*)(ws + 8 * MB); // 16MB, reuses k_bf/v_bf after attention
  u16* Qb   = (u16*)(ws + 24 * MB);
  u16* Kb   = (u16*)(ws + 32 * MB);
  u16* Vt   = (u16*)(ws + 40 * MB);
  u16* Wqt  = (u16*)(ws + 48 * MB);
  u16* Wkt  = (u16*)(ws + 50 * MB);
  u16* Wvt  = (u16*)(ws + 52 * MB);
  u16* Wot  = (u16*)(ws + 54 * MB);
  unsigned* mbits = (unsigned*)(ws + 56 * MB);
  float* ctxf = (float*)(ws + 57 * MB);
  u16* ctx2 = q_bf;

  convert3_kernel<<<dim3(2048, 3), 256, 0, stream>>>(query, key_, value, q_bf, k_bf, v_bf);
  transw_kernel<<<dim3(32, 32, 4), dim3(32, 8), 0, stream>>>(Wq, Wk, Wv, Wo, Wqt, Wkt, Wvt, Wot);
  packmask_kernel<<<32768, 256, 0, stream>>>(mask, mbits);
  ctx_kernel<<<16, 256, 0, stream>>>(mc, Wc, bc, ctxf);

  GemmParams gp;
  gp.A0 = q_bf; gp.A1 = k_bf; gp.A2 = v_bf; gp.A3 = ctx2;
  gp.W0 = Wqt;  gp.W1 = Wkt;  gp.W2 = Wvt;  gp.W3 = Wot;
  gp.b0 = bq;   gp.b1 = bk;   gp.b2 = bv;   gp.b3 = bo;
  gp.ctx = ctxf; gp.resid = query;
  gp.outQ = Qb; gp.outK = Kb; gp.outV = Vt; gp.outX = X;
  gp.which = -1;
  gemm_kernel<<<dim3(8, 32, 3), 256, 0, stream>>>(gp);

  attn_kernel<<<dim3(32, 32), 256, 0, stream>>>(Qb, Kb, Vt, mbits, ctx2);

  gp.which = 3;
  gemm_kernel<<<dim3(8, 32, 1), 256, 0, stream>>>(gp);

  ln_kernel<<<4096, 256, 0, stream>>>(X, lng, lnb, outp);
}

// Round 2
// 222.069 us; speedup vs baseline: 1.2431x; 1.2431x over previous
//
#include <hip/hip_runtime.h>
#include <cstdint>

typedef unsigned short u16;
typedef __attribute__((ext_vector_type(8))) short s16x8;
typedef __attribute__((ext_vector_type(8))) unsigned short u16x8;
typedef __attribute__((ext_vector_type(4))) float f32x4;
typedef __attribute__((ext_vector_type(16))) float f32x16;
typedef __attribute__((ext_vector_type(2))) unsigned uint2v;
typedef __attribute__((ext_vector_type(4))) unsigned uint4v;

__device__ inline u16 f2bf(float f){
  union { float f; uint32_t u; } v; v.f = f;
  uint32_t r = v.u + 0x7fffu + ((v.u >> 16) & 1u);
  return (u16)(r >> 16);
}

__device__ inline f32x4 mfma16(s16x8 a, s16x8 b, f32x4 c){
  return __builtin_amdgcn_mfma_f32_16x16x32_bf16(a, b, c, 0, 0, 0);
}
__device__ inline f32x16 mfma32(s16x8 a, s16x8 b, f32x16 c){
  return __builtin_amdgcn_mfma_f32_32x32x16_bf16(a, b, c, 0, 0, 0);
}
__device__ inline unsigned cvtpk(float a, float b){
  unsigned r;
  asm("v_cvt_pk_bf16_f32 %0, %1, %2" : "=v"(r) : "v"(a), "v"(b));
  return r;
}
__device__ inline float exp2a(float x){
  float r;
  asm("v_exp_f32 %0, %1" : "=v"(r) : "v"(x));
  return r;
}
__device__ inline void glds16(const u16* g, u16* l){
  __builtin_amdgcn_global_load_lds((const __attribute__((address_space(1))) void*)g,
                                   (__attribute__((address_space(3))) void*)l, 16, 0, 0);
}
__device__ inline void glds4(const unsigned* g, unsigned* l){
  __builtin_amdgcn_global_load_lds((const __attribute__((address_space(1))) void*)g,
                                   (__attribute__((address_space(3))) void*)l, 4, 0, 0);
}

// ---------------------------------------------------------------- convert q/k/v to bf16
__global__ __launch_bounds__(256) void convert3_kernel(
    const float* __restrict__ q, const float* __restrict__ k, const float* __restrict__ v,
    u16* __restrict__ qo, u16* __restrict__ ko, u16* __restrict__ vo){
  const float* src = (blockIdx.y == 0) ? q : (blockIdx.y == 1) ? k : v;
  u16* dst = (blockIdx.y == 0) ? qo : (blockIdx.y == 1) ? ko : vo;
  size_t i = ((size_t)blockIdx.x * 256 + threadIdx.x) * 8;
  float4 a = *(const float4*)(src + i);
  float4 b = *(const float4*)(src + i + 4);
  u16x8 o = { f2bf(a.x), f2bf(a.y), f2bf(a.z), f2bf(a.w),
              f2bf(b.x), f2bf(b.y), f2bf(b.z), f2bf(b.w) };
  *(u16x8*)(dst + i) = o;
}

// ---------------------------------------------------------------- transpose+convert weights
__global__ void transw_kernel(
    const float* __restrict__ W0, const float* __restrict__ W1,
    const float* __restrict__ W2, const float* __restrict__ W3,
    u16* __restrict__ T0, u16* __restrict__ T1, u16* __restrict__ T2, u16* __restrict__ T3){
  const float* W = (blockIdx.z == 0) ? W0 : (blockIdx.z == 1) ? W1 : (blockIdx.z == 2) ? W2 : W3;
  u16* T = (blockIdx.z == 0) ? T0 : (blockIdx.z == 1) ? T1 : (blockIdx.z == 2) ? T2 : T3;
  __shared__ float t[32][33];
  int n0 = blockIdx.x * 32, k0 = blockIdx.y * 32;
  int tx = threadIdx.x, ty = threadIdx.y; // (32,8)
  #pragma unroll
  for (int j = 0; j < 4; j++)
    t[ty + j*8][tx] = W[(size_t)(k0 + ty + j*8) * 1024 + n0 + tx];
  __syncthreads();
  #pragma unroll
  for (int j = 0; j < 4; j++)
    T[(size_t)(n0 + ty + j*8) * 1024 + k0 + tx] = f2bf(t[tx][ty + j*8]);
}

// ---------------------------------------------------------------- pack mask to bits
__global__ __launch_bounds__(256) void packmask_kernel(const int* __restrict__ mask,
                                                       unsigned* __restrict__ bits){
  size_t i = (size_t)blockIdx.x * 256 + threadIdx.x;
  int v = mask[i];
  unsigned long long bal = __ballot(v != 0);
  int lane = threadIdx.x & 63;
  if (lane == 0)       bits[i >> 5] = (unsigned)bal;
  else if (lane == 32) bits[i >> 5] = (unsigned)(bal >> 32);
}

// ---------------------------------------------------------------- ctx = market_context @ Wc + bc
__global__ __launch_bounds__(256) void ctx_kernel(const float* __restrict__ mc,
                                                  const float* __restrict__ Wc,
                                                  const float* __restrict__ bc,
                                                  float* __restrict__ ctx){
  int c = threadIdx.x & 63, kk = threadIdx.x >> 6;
  int col = blockIdx.x * 64 + c;
  float a0 = 0.f, a1 = 0.f;
  for (int k = kk * 256; k < kk * 256 + 256; k++){
    float wv = Wc[(size_t)k * 1024 + col];
    a0 += mc[k] * wv;
    a1 += mc[1024 + k] * wv;
  }
  __shared__ float red[2][4][64];
  red[0][kk][c] = a0; red[1][kk][c] = a1;
  __syncthreads();
  if (threadIdx.x < 64){
    int cc = threadIdx.x;
    ctx[blockIdx.x*64 + cc] = red[0][0][cc] + red[0][1][cc] + red[0][2][cc] + red[0][3][cc]
                              + bc[blockIdx.x*64 + cc];
  } else if (threadIdx.x < 128){
    int cc = threadIdx.x - 64;
    ctx[1024 + blockIdx.x*64 + cc] = red[1][0][cc] + red[1][1][cc] + red[1][2][cc] + red[1][3][cc]
                                     + bc[blockIdx.x*64 + cc];
  }
}

// ---------------------------------------------------------------- GEMM (global_load_lds staging)
struct GemmParams {
  const u16* A0; const u16* A1; const u16* A2; const u16* A3;
  const u16* W0; const u16* W1; const u16* W2; const u16* W3;
  const float* b0; const float* b1; const float* b2; const float* b3;
  const float* ctx; const float* resid;
  u16* outQ; u16* outK; u16* outV; float* outX;
  int which;
};

__global__ __launch_bounds__(256) void gemm_kernel(GemmParams P){
  int z = (P.which < 0) ? blockIdx.z : P.which;
  const u16* A; const u16* W;
  if (z == 0){ A = P.A0; W = P.W0; }
  else if (z == 1){ A = P.A1; W = P.W1; }
  else if (z == 2){ A = P.A2; W = P.W2; }
  else { A = P.A3; W = P.W3; }
  const int K = 1024;
  int m0 = blockIdx.y * 128, n0 = blockIdx.x * 128;
  __shared__ u16 Asm[128 * 64];
  __shared__ u16 Bsm[128 * 64];
  int tid = threadIdx.x, lane = tid & 63, w = tid >> 6;
  int li = lane & 15, lq = lane >> 4;
  int wm = w >> 1, wn = w & 1;
  f32x4 zero = {0.f, 0.f, 0.f, 0.f};
  f32x4 acc[4][4];
  #pragma unroll
  for (int i = 0; i < 4; i++)
    #pragma unroll
    for (int j = 0; j < 4; j++) acc[i][j] = zero;

  for (int kt = 0; kt < 16; ++kt){
    int k0 = kt * 64;
    __syncthreads();
    #pragma unroll
    for (int i = 0; i < 4; i++){
      int u0 = i * 256 + (w << 6);
      int u = u0 + lane, row = u >> 3, slot = u & 7;
      glds16(A + (size_t)(m0 + row) * K + k0 + ((slot ^ (row & 7)) << 3), &Asm[u0 * 8]);
      glds16(W + (size_t)(n0 + row) * K + k0 + ((slot ^ (row & 7)) << 3), &Bsm[u0 * 8]);
    }
    __syncthreads();
    #pragma unroll
    for (int ks = 0; ks < 2; ++ks){
      s16x8 af[4], bfr[4];
      #pragma unroll
      for (int mb = 0; mb < 4; mb++){
        int row = wm * 64 + mb * 16 + li, slot = ks * 4 + lq;
        af[mb] = *(const s16x8*)&Asm[row * 64 + ((slot ^ (row & 7)) << 3)];
      }
      #pragma unroll
      for (int nb = 0; nb < 4; nb++){
        int row = wn * 64 + nb * 16 + li, slot = ks * 4 + lq;
        bfr[nb] = *(const s16x8*)&Bsm[row * 64 + ((slot ^ (row & 7)) << 3)];
      }
      #pragma unroll
      for (int mb = 0; mb < 4; mb++)
        #pragma unroll
        for (int nb = 0; nb < 4; nb++)
          acc[mb][nb] = mfma16(af[mb], bfr[nb], acc[mb][nb]);
    }
  }
  const float* bias = (z == 0) ? P.b0 : (z == 1) ? P.b1 : (z == 2) ? P.b2 : P.b3;
  #pragma unroll
  for (int mb = 0; mb < 4; mb++){
    #pragma unroll
    for (int nb = 0; nb < 4; nb++){
      int colL = wn * 64 + nb * 16 + li; int col = n0 + colL;
      float bcol = bias[col];
      #pragma unroll
      for (int r = 0; r < 4; r++){
        int row = m0 + wm * 64 + mb * 16 + lq * 4 + r;
        float v = acc[mb][nb][r] + bcol;
        if (z == 0){
          P.outQ[(size_t)row * 1024 + col] = f2bf(v);
        } else if (z == 1){
          v += P.ctx[(size_t)(row >> 11) * 1024 + col];
          P.outK[(size_t)row * 1024 + col] = f2bf(v);
        } else if (z == 2){
          int b = row >> 11, s = row & 2047, h = col >> 6, dk = col & 63;
          P.outV[(((size_t)(b * 16 + h) * 64 + dk) << 11) + s] = f2bf(v);
        } else {
          v += P.resid[(size_t)row * 1024 + col];
          P.outX[(size_t)row * 1024 + col] = v;
        }
      }
    }
  }
}

// ---------------------------------------------------------------- flash attention (swapped 32x32, in-reg softmax)
// grid (S/128, B*H), block 256 = 4 waves; wave w owns q rows w*32..w*32+32
__global__ __launch_bounds__(256) void attn_kernel(
    const u16* __restrict__ Qg, const u16* __restrict__ Kg, const u16* __restrict__ Vtg,
    const unsigned* __restrict__ mbits, u16* __restrict__ ctx2){
  __shared__ u16 Qs[128 * 64];   // reused as O-tile at end
  __shared__ u16 Ks[64 * 64];
  __shared__ u16 Vs[64 * 64];
  __shared__ unsigned Ms[256];
  int tid = threadIdx.x, lane = tid & 63, w = tid >> 6;
  int l31 = lane & 31, hi = lane >> 5;
  int q0 = blockIdx.x * 128, bh = blockIdx.y, b = bh >> 4, h = bh & 15;
  const float CK = 0.18033688011f; // log2(e)/8

  // stage Q [128][64] via global_load_lds, source pre-swizzled
  #pragma unroll
  for (int i = 0; i < 4; i++){
    int u0 = i * 256 + (w << 6);
    int u = u0 + lane, row = u >> 3, slot = u & 7;
    glds16(Qg + (size_t)(b * 2048 + q0 + row) * 1024 + h * 64 + ((slot ^ (row & 7)) << 3),
           &Qs[u0 * 8]);
  }
  __syncthreads();
  // Q fragments (B-operand): q = w*32 + l31, k = ks*16 + hi*8 + e
  s16x8 qf[4];
  int qrow = w * 32 + l31;
  #pragma unroll
  for (int ks = 0; ks < 4; ks++){
    int slot = ks * 2 + hi;
    qf[ks] = *(const s16x8*)&Qs[qrow * 64 + ((slot ^ (qrow & 7)) << 3)];
  }

  f32x16 accO[2];
  #pragma unroll
  for (int d = 0; d < 2; d++)
    #pragma unroll
    for (int r = 0; r < 16; r++) accO[d][r] = 0.f;
  float mr = -3.0e38f, lsum = 0.f;

  for (int kt = 0; kt < 32; ++kt){
    int kv0 = kt * 64;
    __syncthreads();
    #pragma unroll
    for (int i = 0; i < 2; i++){
      int u0 = i * 256 + (w << 6);
      int u = u0 + lane, row = u >> 3, slot = u & 7;
      glds16(Kg + (size_t)(b * 2048 + kv0 + row) * 1024 + h * 64 + ((slot ^ (row & 7)) << 3),
             &Ks[u0 * 8]);
      glds16(Vtg + (((size_t)(bh * 64 + row)) << 11) + kv0 + ((slot ^ (row & 7)) << 3),
             &Vs[u0 * 8]);
    }
    {
      int t = (w << 6) + lane;
      glds4(mbits + (size_t)(b * 2048 + q0 + (t >> 1)) * 64 + kt * 2 + (t & 1), &Ms[w << 6]);
    }
    __syncthreads();

    // S^T = K · Q : lane holds q=w*32+l31; kv = j*32 + (reg&3)+8*(reg>>2)+4*hi
    f32x16 S[2];
    #pragma unroll
    for (int j = 0; j < 2; j++){
      #pragma unroll
      for (int r = 0; r < 16; r++) S[j][r] = 0.f;
      #pragma unroll
      for (int ks = 0; ks < 4; ks++){
        int krow = j * 32 + l31, slot = ks * 2 + hi;
        s16x8 kf = *(const s16x8*)&Ks[krow * 64 + ((slot ^ (krow & 7)) << 3)];
        S[j] = mfma32(kf, qf[ks], S[j]);
      }
    }
    // mask + tile max (raw scale)
    unsigned mw0 = Ms[((w << 5) | l31) << 1];
    unsigned mw1 = Ms[(((w << 5) | l31) << 1) + 1];
    unsigned mh0 = mw0 >> (hi << 2), mh1 = mw1 >> (hi << 2);
    float pmx[4] = {-3.0e38f, -3.0e38f, -3.0e38f, -3.0e38f};
    #pragma unroll
    for (int j = 0; j < 2; j++){
      unsigned mh = j ? mh1 : mh0;
      #pragma unroll
      for (int rg = 0; rg < 16; rg++){
        int pos = (rg & 3) + ((rg >> 2) << 3);
        float x = S[j][rg];
        x = ((mh >> pos) & 1u) ? x : -3.0e38f;
        S[j][rg] = x;
        pmx[rg & 3] = fmaxf(pmx[rg & 3], x);
      }
    }
    float pm = fmaxf(fmaxf(pmx[0], pmx[1]), fmaxf(pmx[2], pmx[3]));
    pm = fmaxf(pm, __shfl_xor(pm, 32, 64));
    if (__any(pm > mr + 64.f)){   // defer-max: raw 64 == scaled 8
      float mnew = fmaxf(mr, pm);
      float alpha = exp2a((mr - mnew) * CK);
      lsum *= alpha;
      #pragma unroll
      for (int d = 0; d < 2; d++)
        #pragma unroll
        for (int r = 0; r < 16; r++) accO[d][r] *= alpha;
      mr = mnew;
    }
    float mrK = mr * CK;
    float ts[4] = {0.f, 0.f, 0.f, 0.f};
    #pragma unroll
    for (int j = 0; j < 2; j++)
      #pragma unroll
      for (int rg = 0; rg < 16; rg++){
        float p = exp2a(S[j][rg] * CK - mrK);
        S[j][rg] = p;
        ts[rg & 3] += p;
      }
    float tsum = (ts[0] + ts[1]) + (ts[2] + ts[3]);
    tsum += __shfl_xor(tsum, 32, 64);
    lsum += tsum;
    // pack P -> bf16 B-fragments via cvt_pk + permlane32_swap
    s16x8 pf[4];
    #pragma unroll
    for (int j = 0; j < 2; j++){
      #pragma unroll
      for (int hs = 0; hs < 2; hs++){
        int rb = hs * 8;
        unsigned A0 = cvtpk(S[j][rb + 0], S[j][rb + 1]);
        unsigned A1 = cvtpk(S[j][rb + 2], S[j][rb + 3]);
        unsigned B0 = cvtpk(S[j][rb + 4], S[j][rb + 5]);
        unsigned B1 = cvtpk(S[j][rb + 6], S[j][rb + 7]);
        uint2v r01 = __builtin_amdgcn_permlane32_swap(A0, B0, false, false);
        uint2v r23 = __builtin_amdgcn_permlane32_swap(A1, B1, false, false);
        uint4v uu = { r01[0], r23[0], r01[1], r23[1] };
        pf[j * 2 + hs] = *(s16x8*)&uu;
      }
    }
    // O^T += V^T · P
    #pragma unroll
    for (int c = 0; c < 4; c++){
      #pragma unroll
      for (int dh = 0; dh < 2; dh++){
        int drow = dh * 32 + l31, slot = c * 2 + hi;
        s16x8 vf = *(const s16x8*)&Vs[drow * 64 + ((slot ^ (drow & 7)) << 3)];
        accO[dh] = mfma32(vf, pf[c], accO[dh]);
      }
    }
  }
  // transpose O^T through LDS (reuse Qs), then coalesced store
  __syncthreads();
  float inv = 1.f / lsum;
  u16* Ot = Qs;
  int qr = w * 32 + l31;
  #pragma unroll
  for (int dh = 0; dh < 2; dh++){
    #pragma unroll
    for (int rg = 0; rg < 16; rg += 2){
      int dk = dh * 32 + (rg & 3) + ((rg >> 2) << 3) + (hi << 2);
      unsigned pk = cvtpk(accO[dh][rg] * inv, accO[dh][rg + 1] * inv);
      *(unsigned*)&Ot[qr * 64 + (((dk >> 3) ^ (qr & 7)) << 3) + (dk & 7)] = pk;
    }
  }
  __syncthreads();
  #pragma unroll
  for (int i = 0; i < 4; i++){
    int u = i * 256 + tid, row = u >> 3, slot = u & 7;
    u16x8 vv = *(const u16x8*)&Ot[row * 64 + ((slot ^ (row & 7)) << 3)];
    *(u16x8*)(ctx2 + (size_t)(b * 2048 + q0 + row) * 1024 + h * 64 + slot * 8) = vv;
  }
}

// ---------------------------------------------------------------- LayerNorm
__global__ __launch_bounds__(256) void ln_kernel(const float* __restrict__ X,
                                                 const float* __restrict__ g,
                                                 const float* __restrict__ bb,
                                                 float* __restrict__ out){
  size_t row = blockIdx.x;
  const float* x = X + row * 1024;
  int tid = threadIdx.x;
  float4 v = *(const float4*)(x + tid * 4);
  float s = v.x + v.y + v.z + v.w;
  float s2 = v.x*v.x + v.y*v.y + v.z*v.z + v.w*v.w;
  #pragma unroll
  for (int o = 1; o < 64; o <<= 1){
    s += __shfl_xor(s, o, 64);
    s2 += __shfl_xor(s2, o, 64);
  }
  __shared__ float rs[4], rs2[4];
  int w = tid >> 6;
  if ((tid & 63) == 0){ rs[w] = s; rs2[w] = s2; }
  __syncthreads();
  s = rs[0] + rs[1] + rs[2] + rs[3];
  s2 = rs2[0] + rs2[1] + rs2[2] + rs2[3];
  float mu = s * (1.f / 1024.f);
  float var = s2 * (1.f / 1024.f) - mu * mu;
  float rstd = rsqrtf(var + 1e-5f);
  float4 gg = *(const float4*)(g + tid * 4);
  float4 bt = *(const float4*)(bb + tid * 4);
  float4 o;
  o.x = (v.x - mu) * rstd * gg.x + bt.x;
  o.y = (v.y - mu) * rstd * gg.y + bt.y;
  o.z = (v.z - mu) * rstd * gg.z + bt.z;
  o.w = (v.w - mu) * rstd * gg.w + bt.w;
  *(float4*)(out + row * 1024 + tid * 4) = o;
}

// ----------------------------------------------------------------
extern "C" void kernel_launch(void* const* d_in, const int* in_sizes, int n_in,
                              void* d_out, int out_size, void* d_ws, size_t ws_size,
                              hipStream_t stream){
  const float* query = (const float*)d_in[0];
  const float* key_  = (const float*)d_in[1];
  const float* value = (const float*)d_in[2];
  const int*   mask  = (const int*)d_in[3];
  const float* mc    = (const float*)d_in[4];
  const float* Wq = (const float*)d_in[5];  const float* bq = (const float*)d_in[6];
  const float* Wk = (const float*)d_in[7];  const float* bk = (const float*)d_in[8];
  const float* Wv = (const float*)d_in[9];  const float* bv = (const float*)d_in[10];
  const float* Wo = (const float*)d_in[11]; const float* bo = (const float*)d_in[12];
  const float* Wc = (const float*)d_in[13]; const float* bc = (const float*)d_in[14];
  const float* lng = (const float*)d_in[15]; const float* lnb = (const float*)d_in[16];
  float* outp = (float*)d_out;
  uint8_t* ws = (uint8_t*)d_ws;
  const size_t MB = (size_t)1 << 20;
  if (ws_size < 58 * MB) return;

  u16* q_bf = (u16*)(ws + 0);
  u16* k_bf = (u16*)(ws + 8 * MB);
  u16* v_bf = (u16*)(ws + 16 * MB);
  float* X  = (float*)(ws + 8 * MB);
  u16* Qb   = (u16*)(ws + 24 * MB);
  u16* Kb   = (u16*)(ws + 32 * MB);
  u16* Vt   = (u16*)(ws + 40 * MB);
  u16* Wqt  = (u16*)(ws + 48 * MB);
  u16* Wkt  = (u16*)(ws + 50 * MB);
  u16* Wvt  = (u16*)(ws + 52 * MB);
  u16* Wot  = (u16*)(ws + 54 * MB);
  unsigned* mbits = (unsigned*)(ws + 56 * MB);
  float* ctxf = (float*)(ws + 57 * MB);
  u16* ctx2 = q_bf;

  convert3_kernel<<<dim3(2048, 3), 256, 0, stream>>>(query, key_, value, q_bf, k_bf, v_bf);
  transw_kernel<<<dim3(32, 32, 4), dim3(32, 8), 0, stream>>>(Wq, Wk, Wv, Wo, Wqt, Wkt, Wvt, Wot);
  packmask_kernel<<<32768, 256, 0, stream>>>(mask, mbits);
  ctx_kernel<<<16, 256, 0, stream>>>(mc, Wc, bc, ctxf);

  GemmParams gp;
  gp.A0 = q_bf; gp.A1 = k_bf; gp.A2 = v_bf; gp.A3 = ctx2;
  gp.W0 = Wqt;  gp.W1 = Wkt;  gp.W2 = Wvt;  gp.W3 = Wot;
  gp.b0 = bq;   gp.b1 = bk;   gp.b2 = bv;   gp.b3 = bo;
  gp.ctx = ctxf; gp.resid = query;
  gp.outQ = Qb; gp.outK = Kb; gp.outV = Vt; gp.outX = X;
  gp.which = -1;
  gemm_kernel<<<dim3(8, 32, 3), 256, 0, stream>>>(gp);

  attn_kernel<<<dim3(16, 32), 256, 0, stream>>>(Qb, Kb, Vt, mbits, ctx2);

  gp.which = 3;
  gemm_kernel<<<dim3(8, 32, 1), 256, 0, stream>>>(gp);

  ln_kernel<<<4096, 256, 0, stream>>>(X, lng, lnb, outp);
}